// Round 6
// baseline (401.145 us; speedup 1.0000x reference)
//
#include <hip/hip_runtime.h>
#include <math.h>

// NeRF ray-march forward (MipRayMarcher2), LDS-transposed.
// Block = 128 threads / 32 rays. Load phase: dense coalesced global reads,
// transpose-write into LDS [sample][ray] (PAD=34 -> conflict-light).
// March phase: quad-per-ray from LDS (boundaries are LDS reads, no shuffles),
// scalar serial march, 3-shuffle quad scan, 2-shuffle quad reduction.
// Store phase: weights staged in LDS, cooperatively stored dense.
// nRays = 262144, 48 samples, 47 intervals.

#define S_SAMPLES 48
#define S_INTERVALS 47
#define RB 32   // rays per block
#define BT 128  // threads per block
#define PAD 34  // LDS row stride in dwords; 34 == 2 (mod 32)

__device__ __forceinline__ unsigned f2u_sortable(float f) {
    unsigned u = __float_as_uint(f);
    return (u & 0x80000000u) ? ~u : (u | 0x80000000u);
}
__device__ __forceinline__ float u2f_sortable(unsigned u) {
    return (u & 0x80000000u) ? __uint_as_float(u ^ 0x80000000u)
                             : __uint_as_float(~u);
}

__global__ void init_ws_kernel(unsigned* ws) {
    ws[0] = 0xFFFFFFFFu;  // min identity
    ws[1] = 0u;           // max identity
}

__global__ __launch_bounds__(BT) void raymarch_kernel(
    const float* __restrict__ colors,     // [nRays, 48, 3]
    const float* __restrict__ densities,  // [nRays, 48]
    const float* __restrict__ depths,     // [nRays, 48]
    unsigned* __restrict__ ws,            // out: sortable-uint gmin/gmax
    float* __restrict__ out_rgb,          // [nRays, 3]
    float* __restrict__ out_depth,        // [nRays] (unclamped here)
    float* __restrict__ out_w,            // [nRays, 47]
    int nRays) {
    __shared__ float sdep[S_SAMPLES][PAD];
    __shared__ float sden[S_SAMPLES][PAD];
    __shared__ float scol[S_SAMPLES * 3][PAD];
    __shared__ float swei[S_INTERVALS][PAD];
    __shared__ float sTex[4][PAD];

    const int tid = threadIdx.x;
    const size_t rayBase = (size_t)blockIdx.x * RB;

    // ================= load phase: dense global -> transposed LDS ==========
    // depths & densities: RB*48 = 1536 dwords each = 384 float4 = 3/thread
    {
        const float4* gdep = (const float4*)(depths + rayBase * S_SAMPLES);
        const float4* gden = (const float4*)(densities + rayBase * S_SAMPLES);
#pragma unroll
        for (int k = 0; k < 3; ++k) {
            int fidx = tid + k * BT;   // float4 index
            int g = fidx * 4;          // dword index; s = g%48 is multiple of 4
            int ray = g / S_SAMPLES;
            int s = g - ray * S_SAMPLES;
            float4 vd = gdep[fidx];
            float4 vn = gden[fidx];
            sdep[s + 0][ray] = vd.x;
            sdep[s + 1][ray] = vd.y;
            sdep[s + 2][ray] = vd.z;
            sdep[s + 3][ray] = vd.w;
            sden[s + 0][ray] = vn.x;
            sden[s + 1][ray] = vn.y;
            sden[s + 2][ray] = vn.z;
            sden[s + 3][ray] = vn.w;
        }
    }
    // colors: RB*144 = 4608 dwords = 36 scalar loads/thread
    {
        const float* gcol = colors + rayBase * (S_SAMPLES * 3);
#pragma unroll
        for (int k = 0; k < 36; ++k) {
            int g = tid + k * BT;
            int ray = g / (S_SAMPLES * 3);
            int cidx = g - ray * (S_SAMPLES * 3);
            scol[cidx][ray] = gcol[g];
        }
    }
    __syncthreads();

    // ================= march phase: quad-per-ray from LDS ==================
    const int r = tid >> 2;      // local ray 0..31
    const int q = tid & 3;       // quad slot: intervals 12q..12q+11
    const int sBase = 12 * q;
    const float LOG2E = 1.4426950408889634f;

    float dPrev = sdep[sBase][r];
    float nPrev = sden[sBase][r];
    float cP0 = scol[3 * sBase + 0][r];
    float cP1 = scol[3 * sBase + 1][r];
    float cP2 = scol[3 * sBase + 2][r];
    const float firstDep = dPrev;  // sample 0 for q==0

    float T = 1.f;
    float a0 = 0.f, a1 = 0.f, a2 = 0.f, aw = 0.f, ad = 0.f;

#pragma unroll
    for (int j = 0; j < 12; ++j) {
        const int s = sBase + j;
        const bool has = (s < S_INTERVALS);       // q==3, j==11 -> false
        const int sn = has ? (s + 1) : S_INTERVALS;  // clamp: valid row 47
        float dN = sdep[sn][r];
        float nN = sden[sn][r];
        float cN0 = scol[3 * sn + 0][r];
        float cN1 = scol[3 * sn + 1][r];
        float cN2 = scol[3 * sn + 2][r];

        float delta = dN - dPrev;
        float xs = (0.5f * (nPrev + nN) - 1.f) * LOG2E;
        float sp2 = fmaxf(xs, 0.f) + log2f(1.f + exp2f(-fabsf(xs)));
        float alpha = has ? (1.f - exp2f(-delta * sp2)) : 0.f;

        float w = alpha * T;
        T *= (1.f - alpha + 1e-10f);
        if (has) swei[s][r] = w;  // local (unscaled) weight

        a0 = fmaf(w, 0.5f * (cP0 + cN0), a0);
        a1 = fmaf(w, 0.5f * (cP1 + cN1), a1);
        a2 = fmaf(w, 0.5f * (cP2 + cN2), a2);
        aw += w;
        ad = fmaf(w, 0.5f * (dPrev + dN), ad);

        dPrev = dN;
        nPrev = nN;
        cP0 = cN0;
        cP1 = cN1;
        cP2 = cN2;
    }

    // ---- exclusive product scan of local transmittance across the quad ----
    float P = T;
    float u1 = __shfl_up(P, 1);
    float pq = (q >= 1) ? P * u1 : P;
    float u2 = __shfl_up(pq, 2);
    float incl = (q >= 2) ? pq * u2 : pq;
    float u3 = __shfl_up(incl, 1);
    float Texc = (q >= 1) ? u3 : 1.f;
    sTex[q][r] = Texc;

    // ---- quad reduction of the 5 sums (scaled by Texc) ----
    a0 *= Texc; a1 *= Texc; a2 *= Texc; aw *= Texc; ad *= Texc;
#pragma unroll
    for (int off = 1; off <= 2; off <<= 1) {
        a0 += __shfl_xor(a0, off);
        a1 += __shfl_xor(a1, off);
        a2 += __shfl_xor(a2, off);
        aw += __shfl_xor(aw, off);
        ad += __shfl_xor(ad, off);
    }

    if (q == 0) {
        size_t ray = rayBase + r;
        size_t rb = ray * 3;
        out_rgb[rb + 0] = fmaf(a0, 2.f, -1.f);
        out_rgb[rb + 1] = fmaf(a1, 2.f, -1.f);
        out_rgb[rb + 2] = fmaf(a2, 2.f, -1.f);
        out_depth[ray] = ad / aw;  // NaN fixed in clamp pass
    }

    // ---- global depth min/max (depths sorted along samples) ----
    float mnd = (q == 0) ? firstDep : INFINITY;  // sample 0
    float mxd = (q == 3) ? dPrev : -INFINITY;    // sample 47
#pragma unroll
    for (int off = 32; off; off >>= 1) {
        mnd = fminf(mnd, __shfl_xor(mnd, off));
        mxd = fmaxf(mxd, __shfl_xor(mxd, off));
    }
    if ((tid & 63) == 0) {
        atomicMin(&ws[0], f2u_sortable(mnd));
        atomicMax(&ws[1], f2u_sortable(mxd));
    }

    __syncthreads();

    // ================= store phase: LDS -> dense global weights ============
    // RB*47 = 1504 dwords = 11 full rounds of 128 + tail of 96
    {
        float* gw = out_w + rayBase * S_INTERVALS;
#pragma unroll
        for (int k = 0; k < 12; ++k) {
            int g = tid + k * BT;
            if (g < RB * S_INTERVALS) {
                int ray = g / S_INTERVALS;
                int s = g - ray * S_INTERVALS;
                int qo = s / 12;  // owning quad
                gw[g] = swei[s][ray] * sTex[qo][ray];
            }
        }
    }
}

__global__ __launch_bounds__(256) void clamp_depth_kernel(
    float* __restrict__ out_depth, const unsigned* __restrict__ ws, int n) {
    int i = blockIdx.x * blockDim.x + threadIdx.x;
    if (i < n) {
        float gmin = u2f_sortable(ws[0]);
        float gmax = u2f_sortable(ws[1]);
        float d = out_depth[i];
        if (isnan(d)) d = INFINITY;  // nan_to_num(nan=inf)
        d = fminf(fmaxf(d, gmin), gmax);
        out_depth[i] = d;
    }
}

extern "C" void kernel_launch(void* const* d_in, const int* in_sizes, int n_in,
                              void* d_out, int out_size, void* d_ws, size_t ws_size,
                              hipStream_t stream) {
    const float* colors = (const float*)d_in[0];
    const float* densities = (const float*)d_in[1];
    const float* depths = (const float*)d_in[2];

    const int nRays = in_sizes[2] / S_SAMPLES;  // 262144

    float* out = (float*)d_out;
    float* out_rgb = out;                        // nRays*3
    float* out_depth = out + (size_t)nRays * 3;  // nRays
    float* out_w = out + (size_t)nRays * 4;      // nRays*47

    unsigned* ws = (unsigned*)d_ws;

    init_ws_kernel<<<1, 1, 0, stream>>>(ws);

    const int nBlocks = nRays / RB;  // 8192
    raymarch_kernel<<<nBlocks, BT, 0, stream>>>(
        colors, densities, depths, ws, out_rgb, out_depth, out_w, nRays);
    clamp_depth_kernel<<<(nRays + 255) / 256, 256, 0, stream>>>(out_depth, ws, nRays);
}

// Round 7
// 75.426 us; speedup vs baseline: 5.3184x; 5.3184x over previous
//
#include <hip/hip_runtime.h>
#include <math.h>

// NeRF ray-march forward (MipRayMarcher2), LDS-transposed, ATOMIC-FREE.
// R6 structure: block = 128 threads / 32 rays, transposed LDS staging for
// coalesced loads+stores. Change vs R6: per-block depth min/max goes to
// d_ws via plain stores (no global atomics -> no L2 serialization tail);
// a 1-block reduce kernel folds 8192 block results into gmin/gmax.
// nRays = 262144, 48 samples, 47 intervals.

#define S_SAMPLES 48
#define S_INTERVALS 47
#define RB 32   // rays per block
#define BT 128  // threads per block
#define PAD 34  // LDS row stride in dwords; 34 == 2 (mod 32)

__global__ __launch_bounds__(BT) void raymarch_kernel(
    const float* __restrict__ colors,     // [nRays, 48, 3]
    const float* __restrict__ densities,  // [nRays, 48]
    const float* __restrict__ depths,     // [nRays, 48]
    float* __restrict__ bmin,             // [nBlocks] per-block depth min
    float* __restrict__ bmax,             // [nBlocks] per-block depth max
    float* __restrict__ out_rgb,          // [nRays, 3]
    float* __restrict__ out_depth,        // [nRays] (unclamped here)
    float* __restrict__ out_w,            // [nRays, 47]
    int nRays) {
    __shared__ float sdep[S_SAMPLES][PAD];
    __shared__ float sden[S_SAMPLES][PAD];
    __shared__ float scol[S_SAMPLES * 3][PAD];
    __shared__ float swei[S_INTERVALS][PAD];
    __shared__ float sTex[4][PAD];
    __shared__ float wmn[2], wmx[2];

    const int tid = threadIdx.x;
    const size_t rayBase = (size_t)blockIdx.x * RB;

    // ================= load phase: dense global -> transposed LDS ==========
    {
        const float4* gdep = (const float4*)(depths + rayBase * S_SAMPLES);
        const float4* gden = (const float4*)(densities + rayBase * S_SAMPLES);
#pragma unroll
        for (int k = 0; k < 3; ++k) {
            int fidx = tid + k * BT;   // float4 index
            int g = fidx * 4;          // dword index; s = g%48 is multiple of 4
            int ray = g / S_SAMPLES;
            int s = g - ray * S_SAMPLES;
            float4 vd = gdep[fidx];
            float4 vn = gden[fidx];
            sdep[s + 0][ray] = vd.x;
            sdep[s + 1][ray] = vd.y;
            sdep[s + 2][ray] = vd.z;
            sdep[s + 3][ray] = vd.w;
            sden[s + 0][ray] = vn.x;
            sden[s + 1][ray] = vn.y;
            sden[s + 2][ray] = vn.z;
            sden[s + 3][ray] = vn.w;
        }
    }
    {
        const float* gcol = colors + rayBase * (S_SAMPLES * 3);
#pragma unroll
        for (int k = 0; k < 36; ++k) {
            int g = tid + k * BT;
            int ray = g / (S_SAMPLES * 3);
            int cidx = g - ray * (S_SAMPLES * 3);
            scol[cidx][ray] = gcol[g];
        }
    }
    __syncthreads();

    // ================= march phase: quad-per-ray from LDS ==================
    const int r = tid >> 2;      // local ray 0..31
    const int q = tid & 3;       // quad slot: intervals 12q..12q+11
    const int sBase = 12 * q;
    const float LOG2E = 1.4426950408889634f;

    float dPrev = sdep[sBase][r];
    float nPrev = sden[sBase][r];
    float cP0 = scol[3 * sBase + 0][r];
    float cP1 = scol[3 * sBase + 1][r];
    float cP2 = scol[3 * sBase + 2][r];
    const float firstDep = dPrev;  // sample 0 for q==0

    float T = 1.f;
    float a0 = 0.f, a1 = 0.f, a2 = 0.f, aw = 0.f, ad = 0.f;

#pragma unroll
    for (int j = 0; j < 12; ++j) {
        const int s = sBase + j;
        const bool has = (s < S_INTERVALS);          // q==3, j==11 -> false
        const int sn = has ? (s + 1) : S_INTERVALS;  // clamp: valid row 47
        float dN = sdep[sn][r];
        float nN = sden[sn][r];
        float cN0 = scol[3 * sn + 0][r];
        float cN1 = scol[3 * sn + 1][r];
        float cN2 = scol[3 * sn + 2][r];

        float delta = dN - dPrev;
        float xs = (0.5f * (nPrev + nN) - 1.f) * LOG2E;
        float sp2 = fmaxf(xs, 0.f) + log2f(1.f + exp2f(-fabsf(xs)));
        float alpha = has ? (1.f - exp2f(-delta * sp2)) : 0.f;

        float w = alpha * T;
        T *= (1.f - alpha + 1e-10f);
        if (has) swei[s][r] = w;  // local (unscaled) weight

        a0 = fmaf(w, 0.5f * (cP0 + cN0), a0);
        a1 = fmaf(w, 0.5f * (cP1 + cN1), a1);
        a2 = fmaf(w, 0.5f * (cP2 + cN2), a2);
        aw += w;
        ad = fmaf(w, 0.5f * (dPrev + dN), ad);

        dPrev = dN;
        nPrev = nN;
        cP0 = cN0;
        cP1 = cN1;
        cP2 = cN2;
    }

    // ---- exclusive product scan of local transmittance across the quad ----
    float P = T;
    float u1 = __shfl_up(P, 1);
    float pq = (q >= 1) ? P * u1 : P;
    float u2 = __shfl_up(pq, 2);
    float incl = (q >= 2) ? pq * u2 : pq;
    float u3 = __shfl_up(incl, 1);
    float Texc = (q >= 1) ? u3 : 1.f;
    sTex[q][r] = Texc;

    // ---- quad reduction of the 5 sums (scaled by Texc) ----
    a0 *= Texc; a1 *= Texc; a2 *= Texc; aw *= Texc; ad *= Texc;
#pragma unroll
    for (int off = 1; off <= 2; off <<= 1) {
        a0 += __shfl_xor(a0, off);
        a1 += __shfl_xor(a1, off);
        a2 += __shfl_xor(a2, off);
        aw += __shfl_xor(aw, off);
        ad += __shfl_xor(ad, off);
    }

    if (q == 0) {
        size_t ray = rayBase + r;
        size_t rb = ray * 3;
        out_rgb[rb + 0] = fmaf(a0, 2.f, -1.f);
        out_rgb[rb + 1] = fmaf(a1, 2.f, -1.f);
        out_rgb[rb + 2] = fmaf(a2, 2.f, -1.f);
        out_depth[ray] = ad / aw;  // NaN fixed in clamp pass
    }

    // ---- per-wave depth min/max (depths sorted along samples) ----
    float mnd = (q == 0) ? firstDep : INFINITY;  // sample 0
    float mxd = (q == 3) ? dPrev : -INFINITY;    // sample 47
#pragma unroll
    for (int off = 32; off; off >>= 1) {
        mnd = fminf(mnd, __shfl_xor(mnd, off));
        mxd = fmaxf(mxd, __shfl_xor(mxd, off));
    }
    if ((tid & 63) == 0) {
        wmn[tid >> 6] = mnd;
        wmx[tid >> 6] = mxd;
    }

    __syncthreads();

    // ---- per-block min/max: plain stores, zero atomics ----
    if (tid == 0) {
        bmin[blockIdx.x] = fminf(wmn[0], wmn[1]);
        bmax[blockIdx.x] = fmaxf(wmx[0], wmx[1]);
    }

    // ================= store phase: LDS -> dense global weights ============
    {
        float* gw = out_w + rayBase * S_INTERVALS;
#pragma unroll
        for (int k = 0; k < 12; ++k) {
            int g = tid + k * BT;
            if (g < RB * S_INTERVALS) {
                int ray = g / S_INTERVALS;
                int s = g - ray * S_INTERVALS;
                int qo = s / 12;  // owning quad
                gw[g] = swei[s][ray] * sTex[qo][ray];
            }
        }
    }
}

// Fold 8192 per-block minima/maxima into g[0]=gmin, g[1]=gmax. One block.
__global__ __launch_bounds__(1024) void reduce_minmax_kernel(
    const float* __restrict__ bmin, const float* __restrict__ bmax,
    float* __restrict__ g, int n) {
    float mn = INFINITY, mx = -INFINITY;
    for (int i = threadIdx.x; i < n; i += 1024) {
        mn = fminf(mn, bmin[i]);
        mx = fmaxf(mx, bmax[i]);
    }
#pragma unroll
    for (int off = 32; off; off >>= 1) {
        mn = fminf(mn, __shfl_xor(mn, off));
        mx = fmaxf(mx, __shfl_xor(mx, off));
    }
    __shared__ float smn[16], smx[16];
    const int wid = threadIdx.x >> 6;
    if ((threadIdx.x & 63) == 0) {
        smn[wid] = mn;
        smx[wid] = mx;
    }
    __syncthreads();
    if (threadIdx.x == 0) {
        float m = INFINITY, M = -INFINITY;
#pragma unroll
        for (int i = 0; i < 16; ++i) {
            m = fminf(m, smn[i]);
            M = fmaxf(M, smx[i]);
        }
        g[0] = m;
        g[1] = M;
    }
}

__global__ __launch_bounds__(256) void clamp_depth_kernel(
    float* __restrict__ out_depth, const float* __restrict__ g, int n) {
    int i = blockIdx.x * blockDim.x + threadIdx.x;
    if (i < n) {
        float gmin = g[0];
        float gmax = g[1];
        float d = out_depth[i];
        if (isnan(d)) d = INFINITY;  // nan_to_num(nan=inf)
        d = fminf(fmaxf(d, gmin), gmax);
        out_depth[i] = d;
    }
}

extern "C" void kernel_launch(void* const* d_in, const int* in_sizes, int n_in,
                              void* d_out, int out_size, void* d_ws, size_t ws_size,
                              hipStream_t stream) {
    const float* colors = (const float*)d_in[0];
    const float* densities = (const float*)d_in[1];
    const float* depths = (const float*)d_in[2];

    const int nRays = in_sizes[2] / S_SAMPLES;  // 262144
    const int nBlocks = nRays / RB;             // 8192

    float* out = (float*)d_out;
    float* out_rgb = out;                        // nRays*3
    float* out_depth = out + (size_t)nRays * 3;  // nRays
    float* out_w = out + (size_t)nRays * 4;      // nRays*47

    // ws layout (floats): [0]=gmin, [1]=gmax, [2 .. 2+nB)=bmin, [2+nB ..)=bmax
    float* wsf = (float*)d_ws;
    float* g = wsf;
    float* bmin = wsf + 2;
    float* bmax = wsf + 2 + nBlocks;

    raymarch_kernel<<<nBlocks, BT, 0, stream>>>(
        colors, densities, depths, bmin, bmax, out_rgb, out_depth, out_w, nRays);
    reduce_minmax_kernel<<<1, 1024, 0, stream>>>(bmin, bmax, g, nBlocks);
    clamp_depth_kernel<<<(nRays + 255) / 256, 256, 0, stream>>>(out_depth, g, nRays);
}

// Round 8
// 59.510 us; speedup vs baseline: 6.7408x; 1.2674x over previous
//
#include <hip/hip_runtime.h>
#include <math.h>

// NeRF ray-march forward (MipRayMarcher2), LDS-transposed, atomic-free,
// LOW-LDS version: colors are NOT staged whole. Using
//   composite_rgb = sum_s c[s] * v[s],  v[s] = 0.5*(w[s-1]+w[s]),
// the march needs only dep/den in LDS; colors stream through a 6.5 KB tile
// (reusing the dead density buffer) in 3 chunks. LDS ~19.5 KB -> 8 blocks/CU.
// Block = 128 threads / 32 rays, quad-per-ray march.
// nRays = 262144, 48 samples, 47 intervals.

#define S_SAMPLES 48
#define S_INTERVALS 47
#define RB 32   // rays per block
#define BT 128  // threads per block
#define PAD 34  // LDS row stride in dwords; 34 == 2 (mod 32)

__global__ __launch_bounds__(BT) void raymarch_kernel(
    const float* __restrict__ colors,     // [nRays, 48, 3]
    const float* __restrict__ densities,  // [nRays, 48]
    const float* __restrict__ depths,     // [nRays, 48]
    float* __restrict__ bmin,             // [nBlocks] per-block depth min
    float* __restrict__ bmax,             // [nBlocks] per-block depth max
    float* __restrict__ out_rgb,          // [nRays, 3]
    float* __restrict__ out_depth,        // [nRays] (unclamped here)
    float* __restrict__ out_w,            // [nRays, 47]
    int nRays) {
    __shared__ float sdep[S_SAMPLES][PAD];   // depths; REUSED as v[s][ray]
    __shared__ float sden[S_SAMPLES][PAD];   // densities; REUSED as color tile
    __shared__ float swei[S_INTERVALS][PAD]; // Texc-scaled weights
    __shared__ float wmn[2], wmx[2];

    const int tid = threadIdx.x;
    const size_t rayBase = (size_t)blockIdx.x * RB;

    // ========== load phase: dense global -> transposed LDS (dep, den) ======
    {
        const float4* gdep = (const float4*)(depths + rayBase * S_SAMPLES);
        const float4* gden = (const float4*)(densities + rayBase * S_SAMPLES);
#pragma unroll
        for (int k = 0; k < 3; ++k) {
            int fidx = tid + k * BT;   // float4 index 0..383
            int g = fidx * 4;          // dword index; s multiple of 4
            int ray = g / S_SAMPLES;
            int s = g - ray * S_SAMPLES;
            float4 vd = gdep[fidx];
            float4 vn = gden[fidx];
            sdep[s + 0][ray] = vd.x;
            sdep[s + 1][ray] = vd.y;
            sdep[s + 2][ray] = vd.z;
            sdep[s + 3][ray] = vd.w;
            sden[s + 0][ray] = vn.x;
            sden[s + 1][ray] = vn.y;
            sden[s + 2][ray] = vn.z;
            sden[s + 3][ray] = vn.w;
        }
    }
    __syncthreads();

    // ========== march phase: quad-per-ray, weights in named registers ======
    const int r = tid >> 2;  // local ray 0..31
    const int q = tid & 3;   // quad slot: intervals 12q..12q+11
    const int sBase = 12 * q;
    const float LOG2E = 1.4426950408889634f;

    float dPrev = sdep[sBase][r];
    float nPrev = sden[sBase][r];
    const float firstDep = dPrev;  // sample 0 for q==0

    float T = 1.f, aw = 0.f, ad = 0.f;
    float w0, w1, w2, w3, w4, w5, w6, w7, w8, w9, w10, w11;

#define MSTEP(W, HAS, ROWN)                                            \
    do {                                                               \
        float dN = sdep[(ROWN)][r];                                    \
        float nN = sden[(ROWN)][r];                                    \
        float delta = dN - dPrev;                                      \
        float xs = (0.5f * (nPrev + nN) - 1.f) * LOG2E;                \
        float sp2 = fmaxf(xs, 0.f) + log2f(1.f + exp2f(-fabsf(xs)));   \
        float alpha = (HAS) ? (1.f - exp2f(-delta * sp2)) : 0.f;       \
        W = alpha * T;                                                 \
        T *= (1.f - alpha + 1e-10f);                                   \
        aw += W;                                                       \
        ad = fmaf(W, 0.5f * (dPrev + dN), ad);                         \
        dPrev = dN;                                                    \
        nPrev = nN;                                                    \
    } while (0)

    MSTEP(w0, true, sBase + 1);
    MSTEP(w1, true, sBase + 2);
    MSTEP(w2, true, sBase + 3);
    MSTEP(w3, true, sBase + 4);
    MSTEP(w4, true, sBase + 5);
    MSTEP(w5, true, sBase + 6);
    MSTEP(w6, true, sBase + 7);
    MSTEP(w7, true, sBase + 8);
    MSTEP(w8, true, sBase + 9);
    MSTEP(w9, true, sBase + 10);
    MSTEP(w10, true, sBase + 11);
    MSTEP(w11, (q < 3), ((q < 3) ? (sBase + 12) : (sBase + 11)));
#undef MSTEP

    // ---- exclusive product scan of local transmittance across the quad ----
    float P = T;
    float u1 = __shfl_up(P, 1);
    float pq = (q >= 1) ? P * u1 : P;
    float u2 = __shfl_up(pq, 2);
    float incl = (q >= 2) ? pq * u2 : pq;
    float u3 = __shfl_up(incl, 1);
    float Texc = (q >= 1) ? u3 : 1.f;

    // ---- store Texc-scaled weights to LDS ----
    swei[sBase + 0][r] = w0 * Texc;
    swei[sBase + 1][r] = w1 * Texc;
    swei[sBase + 2][r] = w2 * Texc;
    swei[sBase + 3][r] = w3 * Texc;
    swei[sBase + 4][r] = w4 * Texc;
    swei[sBase + 5][r] = w5 * Texc;
    swei[sBase + 6][r] = w6 * Texc;
    swei[sBase + 7][r] = w7 * Texc;
    swei[sBase + 8][r] = w8 * Texc;
    swei[sBase + 9][r] = w9 * Texc;
    swei[sBase + 10][r] = w10 * Texc;
    if (q < 3) swei[sBase + 11][r] = w11 * Texc;

    // ---- quad reduction of weight/depth sums ----
    aw *= Texc;
    ad *= Texc;
#pragma unroll
    for (int off = 1; off <= 2; off <<= 1) {
        aw += __shfl_xor(aw, off);
        ad += __shfl_xor(ad, off);
    }
    if (q == 0) out_depth[rayBase + r] = ad / aw;  // NaN fixed in clamp pass

    // ---- per-wave depth min/max (depths sorted along samples) ----
    float mnd = (q == 0) ? firstDep : INFINITY;  // sample 0
    float mxd = (q == 3) ? dPrev : -INFINITY;    // sample 47
#pragma unroll
    for (int off = 32; off; off >>= 1) {
        mnd = fminf(mnd, __shfl_xor(mnd, off));
        mxd = fmaxf(mxd, __shfl_xor(mxd, off));
    }
    if ((tid & 63) == 0) {
        wmn[tid >> 6] = mnd;
        wmx[tid >> 6] = mxd;
    }

    __syncthreads();  // swei complete; sdep/sden now dead

    if (tid == 0) {
        bmin[blockIdx.x] = fminf(wmn[0], wmn[1]);
        bmax[blockIdx.x] = fmaxf(wmx[0], wmx[1]);
    }

    // ========== v-pass: v[s] = 0.5*(w[s-1]+w[s]) into sdep ================
#pragma unroll
    for (int k = 0; k < 12; ++k) {
        int e = tid + k * BT;  // 0..1535
        int s = e >> 5;
        int rr = e & 31;
        float wlo = (s > 0) ? swei[s - 1][rr] : 0.f;
        float whi = (s < S_INTERVALS) ? swei[s][rr] : 0.f;
        sdep[s][rr] = 0.5f * (wlo + whi);
    }

    // ========== weight store: LDS -> dense global ==========================
    {
        float* gw = out_w + rayBase * S_INTERVALS;
#pragma unroll
        for (int k = 0; k < 12; ++k) {
            int g = tid + k * BT;
            if (g < RB * S_INTERVALS) {
                int ray = g / S_INTERVALS;
                int s = g - ray * S_INTERVALS;
                gw[g] = swei[s][ray];
            }
        }
    }

    // ========== color phase: 3 chunks through sden tile ====================
    float a0 = 0.f, a1 = 0.f, a2 = 0.f;
    const float4* gcol4 = (const float4*)(colors + rayBase * (S_SAMPLES * 3));
#pragma unroll
    for (int c = 0; c < 3; ++c) {
        // load chunk c: 48 dwords per ray (16 samples x 3 ch), coalesced
#pragma unroll
        for (int k = 0; k < 3; ++k) {
            int f = tid + k * BT;  // 0..383
            int rr = f / 12;       // ray 0..31
            int i4 = f - rr * 12;  // float4 index within chunk 0..11
            float4 v4 = gcol4[(size_t)rr * 36 + c * 12 + i4];
            int row = i4 * 4;
            sden[row + 0][rr] = v4.x;
            sden[row + 1][rr] = v4.y;
            sden[row + 2][rr] = v4.z;
            sden[row + 3][rr] = v4.w;
        }
        __syncthreads();  // tile ready (and, for c==0, v-pass visible)
#pragma unroll
        for (int i = 0; i < 4; ++i) {
            int sl = 4 * q + i;  // local sample 0..15
            float vv = sdep[c * 16 + sl][r];
            a0 = fmaf(vv, sden[3 * sl + 0][r], a0);
            a1 = fmaf(vv, sden[3 * sl + 1][r], a1);
            a2 = fmaf(vv, sden[3 * sl + 2][r], a2);
        }
        __syncthreads();  // done with tile before next chunk overwrites
    }

    // ---- quad reduction of rgb sums ----
#pragma unroll
    for (int off = 1; off <= 2; off <<= 1) {
        a0 += __shfl_xor(a0, off);
        a1 += __shfl_xor(a1, off);
        a2 += __shfl_xor(a2, off);
    }
    if (q == 0) {
        size_t rb = (rayBase + r) * 3;
        out_rgb[rb + 0] = fmaf(a0, 2.f, -1.f);
        out_rgb[rb + 1] = fmaf(a1, 2.f, -1.f);
        out_rgb[rb + 2] = fmaf(a2, 2.f, -1.f);
    }
}

// Fold 8192 per-block minima/maxima into g[0]=gmin, g[1]=gmax. One block.
__global__ __launch_bounds__(1024) void reduce_minmax_kernel(
    const float* __restrict__ bmin, const float* __restrict__ bmax,
    float* __restrict__ g, int n) {
    float mn = INFINITY, mx = -INFINITY;
    for (int i = threadIdx.x; i < n; i += 1024) {
        mn = fminf(mn, bmin[i]);
        mx = fmaxf(mx, bmax[i]);
    }
#pragma unroll
    for (int off = 32; off; off >>= 1) {
        mn = fminf(mn, __shfl_xor(mn, off));
        mx = fmaxf(mx, __shfl_xor(mx, off));
    }
    __shared__ float smn[16], smx[16];
    const int wid = threadIdx.x >> 6;
    if ((threadIdx.x & 63) == 0) {
        smn[wid] = mn;
        smx[wid] = mx;
    }
    __syncthreads();
    if (threadIdx.x == 0) {
        float m = INFINITY, M = -INFINITY;
#pragma unroll
        for (int i = 0; i < 16; ++i) {
            m = fminf(m, smn[i]);
            M = fmaxf(M, smx[i]);
        }
        g[0] = m;
        g[1] = M;
    }
}

__global__ __launch_bounds__(256) void clamp_depth_kernel(
    float* __restrict__ out_depth, const float* __restrict__ g, int n) {
    int i = blockIdx.x * blockDim.x + threadIdx.x;
    if (i < n) {
        float gmin = g[0];
        float gmax = g[1];
        float d = out_depth[i];
        if (isnan(d)) d = INFINITY;  // nan_to_num(nan=inf)
        d = fminf(fmaxf(d, gmin), gmax);
        out_depth[i] = d;
    }
}

extern "C" void kernel_launch(void* const* d_in, const int* in_sizes, int n_in,
                              void* d_out, int out_size, void* d_ws, size_t ws_size,
                              hipStream_t stream) {
    const float* colors = (const float*)d_in[0];
    const float* densities = (const float*)d_in[1];
    const float* depths = (const float*)d_in[2];

    const int nRays = in_sizes[2] / S_SAMPLES;  // 262144
    const int nBlocks = nRays / RB;             // 8192

    float* out = (float*)d_out;
    float* out_rgb = out;                        // nRays*3
    float* out_depth = out + (size_t)nRays * 3;  // nRays
    float* out_w = out + (size_t)nRays * 4;      // nRays*47

    // ws layout (floats): [0]=gmin, [1]=gmax, [2 .. 2+nB)=bmin, [2+nB ..)=bmax
    float* wsf = (float*)d_ws;
    float* g = wsf;
    float* bmin = wsf + 2;
    float* bmax = wsf + 2 + nBlocks;

    raymarch_kernel<<<nBlocks, BT, 0, stream>>>(
        colors, densities, depths, bmin, bmax, out_rgb, out_depth, out_w, nRays);
    reduce_minmax_kernel<<<1, 1024, 0, stream>>>(bmin, bmax, g, nBlocks);
    clamp_depth_kernel<<<(nRays + 255) / 256, 256, 0, stream>>>(out_depth, g, nRays);
}